// Round 11
// baseline (1868.215 us; speedup 1.0000x reference)
//
#include <hip/hip_runtime.h>
#include <math.h>

#define K_ 64
#define C_ 128
#define NB 16
#define P_ 8000

typedef float f32x4 __attribute__((ext_vector_type(4)));
typedef short s16x8 __attribute__((ext_vector_type(8)));

__device__ __forceinline__ short f2bf(float v) {
    unsigned u = __float_as_uint(v);
    u += 0x7FFFu + ((u >> 16) & 1u);
    return (short)(u >> 16);
}
__device__ __forceinline__ float bf2f(ushort u) { return __uint_as_float(((unsigned)u) << 16); }

// async global->LDS 16B DMA; dest is wave-uniform base + lane*16
__device__ __forceinline__ void stage16(const void* g, void* l) {
    __builtin_amdgcn_global_load_lds(
        (const __attribute__((address_space(1))) void*)g,
        (__attribute__((address_space(3))) void*)l, 16, 0, 0);
}

// ======================= tiled transpose: in[Co][E] -> out[E][Co] (f32) =======================
__global__ void k_transpose_tiled(const float* __restrict__ in, float* __restrict__ out,
                                  int Co, int E)
{
    __shared__ float t[32][33];
    const int e0  = blockIdx.x * 32;
    const int co0 = blockIdx.y * 32;
    for (int i = threadIdx.y; i < 32; i += 8) {
        int co = co0 + i, e = e0 + threadIdx.x;
        t[i][threadIdx.x] = (co < Co && e < E) ? in[(size_t)co * E + e] : 0.f;
    }
    __syncthreads();
    for (int i = threadIdx.y; i < 32; i += 8) {
        int e = e0 + i, co = co0 + threadIdx.x;
        if (e < E && co < Co) out[(size_t)e * Co + co] = t[threadIdx.x][i];
    }
}

// ======================= NCHW f32 -> NHWC bf16 =======================
__global__ void k_nchw_to_nhwc(const float* __restrict__ in, ushort* __restrict__ out,
                               int C, int P)
{
    __shared__ ushort t[32][33];
    const int n  = blockIdx.z;
    const int p0 = blockIdx.x * 32;
    const int c0 = blockIdx.y * 32;
    for (int i = threadIdx.y; i < 32; i += 8) {
        int c = c0 + i, p = p0 + threadIdx.x;
        t[i][threadIdx.x] = (c < C && p < P) ? (ushort)f2bf(in[((size_t)n * C + c) * P + p]) : 0;
    }
    __syncthreads();
    for (int i = threadIdx.y; i < 32; i += 8) {
        int p = p0 + i, c = c0 + threadIdx.x;
        if (p < P && c < C) out[((size_t)n * P + p) * C + c] = t[threadIdx.x][i];
    }
}

// ======================= weight prep: w[Co][Cin][5][5] f32 -> wb[((ck*25+t)*Co+co)*32+cl] bf16 ====
__global__ void k_wprep(const float* __restrict__ w, short* __restrict__ wb,
                        int Co, int Cin, int total)
{
    int idx = blockIdx.x * blockDim.x + threadIdx.x;
    if (idx >= total) return;
    int cl = idx & 31;
    int rest = idx >> 5;
    int co = rest % Co;
    int rest2 = rest / Co;
    int t = rest2 % 25;
    int ck = rest2 / 25;
    float v = w[((size_t)co * Cin + (ck << 5) + cl) * 25 + t];
    wb[idx] = f2bf(v);
}

// ======================= implicit-GEMM conv 5x5 pad 2, bf16 MFMA, channel-last in/out ==========
// block: 256 thr = 4 waves, each owning a distinct 64-co slice. block tile: 256co x 64pos.
// Wave tile 64co x 64pos -> acc[4][4] = 64 VGPR; __launch_bounds__(256,4) caps VGPR at 128
// for 4 waves/SIMD. Weights: REGISTERS via plain global loads (L2-resident), compiler-scheduled
// (unrolled tap loop, no asm). Input: single LDS buffer via global_load_lds, 2 barriers/chunk.
template<int SR, int NC, int WR, int WC16, int IS3>
__global__ __launch_bounds__(256, 4) void k_conv_mfma(
    const ushort* __restrict__ in, const s16x8* __restrict__ wb,
    const float* __restrict__ bias, ushort* __restrict__ outb, float* __restrict__ outf,
    const ushort* __restrict__ zg,
    int Cin, int Co, int H, int W, int WT, int leaky, int nck, int xpc, int PT)
{
    constexpr int NT   = 4;
    constexpr int TOT  = SR * NC * 4;
    constexpr int TOTP = (TOT + 63) & ~63;
    __shared__ s16x8 xin[TOTP];

    const int tid  = threadIdx.x;
    const int lane = tid & 63;
    const int wid  = tid >> 6;
    const int n16  = lane & 15;
    const int g    = lane >> 4;

    // XCD-aware decode: co-blocks partitioned across XCDs -> per-XCD weight set fits L2
    const int lid  = blockIdx.x;
    const int xcd  = lid & 7;
    const int rrr  = lid >> 3;
    const int co_blk = xcd / xpc;
    const int posn = rrr * xpc + (xcd % xpc);
    const int n    = posn / PT;
    const int bx   = posn % PT;

    const int h0    = IS3 ? 0 : (bx / WT) * WR;
    const int w0    = IS3 ? 0 : (bx % WT) * (WC16 * 16);
    const int ks    = IS3 ? (bx >> 1) : 0;
    const int phalf = IS3 ? (bx & 1) : 0;
    const int co0   = co_blk * 256;
    const int cobase = co0 + wid * 64;     // this wave's co slice

    int ph[NT], pw[NT];
    if (IS3) {
        #pragma unroll
        for (int nt = 0; nt < NT; ++nt) {
            int pos = phalf * 64 + nt * 16 + n16;
            int h = pos / 25;
            int w = pos - h * 25;
            if (h > 4) { h = 0; w = 0; }
            ph[nt] = h; pw[nt] = w;
        }
    }

    f32x4 acc[4][NT];
    #pragma unroll
    for (int i = 0; i < 4; ++i)
        #pragma unroll
        for (int j = 0; j < NT; ++j) acc[i][j] = f32x4{0.f, 0.f, 0.f, 0.f};

    const int ck0 = IS3 ? ks * nck : 0;
    const int ckend = ck0 + nck;

    // stage input chunk ck via async DMA (inverse-swizzled global source, linear LDS dest)
    auto stage_input = [&](int ck) {
        for (int c = wid; c * 64 < TOTP; c += 4) {
            int u = c * 64 + lane;
            int row = u / (NC * 4);
            int rem = u - row * (NC * 4);
            int col = rem >> 2;
            int s   = rem & 3;
            int g8  = (s - (col >> 1) - row) & 3;
            int gh = h0 + row - 2, gw = w0 + col - 2;
            const void* src =
                (u < TOT && (unsigned)gh < (unsigned)H && (unsigned)gw < (unsigned)W)
                ? (const void*)(in + ((size_t)(n * H + gh) * W + gw) * Cin + (ck << 5) + (g8 << 3))
                : (const void*)zg;
            stage16(src, (void*)&xin[c * 64]);
        }
    };

    for (int ck = ck0; ck < ckend; ++ck) {
        if (ck != ck0) __syncthreads();    // all waves done reading old xin
        stage_input(ck);
        __syncthreads();                   // drains DMA (vmcnt 0) -> xin ready

        // weight base for this chunk/wave: s16x8 units
        const s16x8* wbase = wb + ((size_t)ck * 25 * Co + cobase + n16) * 4 + g;
        s16x8 wf[4];
        #pragma unroll
        for (int mt = 0; mt < 4; ++mt) wf[mt] = wbase[mt * 64];

        #pragma unroll
        for (int t = 0; t < 25; ++t) {
            s16x8 wfn[4];
            if (t < 24) {
                const s16x8* wn = wbase + (size_t)(t + 1) * Co * 4;
                #pragma unroll
                for (int mt = 0; mt < 4; ++mt) wfn[mt] = wn[mt * 64];
            }
            const int r = t / 5, s = t - (t / 5) * 5;

            s16x8 bf[NT];
            #pragma unroll
            for (int nt = 0; nt < NT; ++nt) {
                int row, col;
                if (IS3) { row = ph[nt] + r; col = pw[nt] + s; }
                else {
                    int rr = nt / WC16, cc = nt - rr * WC16;
                    row = rr + r;
                    col = cc * 16 + n16 + s;
                }
                bf[nt] = xin[(row * NC + col) * 4 + ((g + (col >> 1) + row) & 3)];
            }
            #pragma unroll
            for (int mt = 0; mt < 4; ++mt)
                #pragma unroll
                for (int nt = 0; nt < NT; ++nt)
                    acc[mt][nt] = __builtin_amdgcn_mfma_f32_16x16x32_bf16(
                        wf[mt], bf[nt], acc[mt][nt], 0, 0, 0);
            if (t < 24) {
                #pragma unroll
                for (int mt = 0; mt < 4; ++mt) wf[mt] = wfn[mt];
            }
        }
    }

    // ---- epilogue: C/D layout col=lane&15 (pos), row=g*4+reg (co) ----
    if (IS3) {
        #pragma unroll
        for (int mt = 0; mt < 4; ++mt) {
            #pragma unroll
            for (int reg = 0; reg < 4; ++reg) {
                const int co = cobase + mt * 16 + g * 4 + reg;
                #pragma unroll
                for (int nt = 0; nt < NT; ++nt) {
                    int pos = phalf * 64 + nt * 16 + n16;
                    if (pos < 125)
                        outf[((size_t)(ks * NB + n) * Co + co) * 125 + pos] = acc[mt][nt][reg];
                }
            }
        }
    } else {
        #pragma unroll
        for (int mt = 0; mt < 4; ++mt) {
            const int cb = cobase + mt * 16 + g * 4;
            const float b0 = bias[cb + 0];
            const float b1 = bias[cb + 1];
            const float b2 = bias[cb + 2];
            const float b3 = bias[cb + 3];
            #pragma unroll
            for (int nt = 0; nt < NT; ++nt) {
                int rr = nt / WC16, cc = nt - rr * WC16;
                int h  = h0 + rr;
                int wp = w0 + cc * 16 + n16;
                if (h < H && wp < W) {
                    float v0 = acc[mt][nt][0] + b0;
                    float v1 = acc[mt][nt][1] + b1;
                    float v2 = acc[mt][nt][2] + b2;
                    float v3 = acc[mt][nt][3] + b3;
                    if (leaky) {
                        v0 = (v0 >= 0.f) ? v0 : 0.2f * v0;
                        v1 = (v1 >= 0.f) ? v1 : 0.2f * v1;
                        v2 = (v2 >= 0.f) ? v2 : 0.2f * v2;
                        v3 = (v3 >= 0.f) ? v3 : 0.2f * v3;
                    }
                    ushort4 pkd;
                    pkd.x = (ushort)f2bf(v0);
                    pkd.y = (ushort)f2bf(v1);
                    pkd.z = (ushort)f2bf(v2);
                    pkd.w = (ushort)f2bf(v3);
                    *(ushort4*)(outb + ((size_t)(n * H + h) * W + wp) * Co + cb) = pkd;
                }
            }
        }
    }
}

// ======================= VLAD partial: softmax assignment + partial einsum =======================
__global__ __launch_bounds__(256) void k_vlad_partial(
    const float* __restrict__ x,        // [N][C][P]
    const float* __restrict__ convw_t,  // [C][K]
    const float* __restrict__ convb,    // [K]
    float* __restrict__ pv,             // [N][125][K][C]
    float* __restrict__ pa)             // [N][125][K]
{
    __shared__ float xs[C_][64];
    __shared__ float als[64][K_];
    __shared__ float pgsum[4][K_];

    const int tid = threadIdx.x;
    const int chunk = blockIdx.x;    // 0..124
    const int n = blockIdx.y;        // 0..15
    const int p0 = chunk * 64;

    const float* xn = x + (size_t)n * C_ * P_ + p0;
    for (int i = tid; i < C_ * 64; i += 256) {
        int c = i >> 6, pp = i & 63;
        xs[c][pp] = xn[(size_t)c * P_ + pp];
    }
    __syncthreads();

    const int k  = tid & 63;
    const int pg = tid >> 6;

    float sa[16];
    const float bk = convb[k];
    #pragma unroll
    for (int j = 0; j < 16; ++j) sa[j] = bk;
    for (int c = 0; c < C_; ++c) {
        float wv = convw_t[c * K_ + k];
        const float4* xp = (const float4*)&xs[c][pg * 16];
        #pragma unroll
        for (int q = 0; q < 4; ++q) {
            float4 xv = xp[q];
            sa[q*4+0] += wv * xv.x;
            sa[q*4+1] += wv * xv.y;
            sa[q*4+2] += wv * xv.z;
            sa[q*4+3] += wv * xv.w;
        }
    }

    float asum_loc = 0.f;
    #pragma unroll
    for (int j = 0; j < 16; ++j) {
        float m = sa[j];
        for (int d = 32; d >= 1; d >>= 1) m = fmaxf(m, __shfl_xor(m, d));
        float e = __expf(sa[j] - m);
        float s = e;
        for (int d = 32; d >= 1; d >>= 1) s += __shfl_xor(s, d);
        float a = e / s;
        als[pg * 16 + j][k] = a;
        asum_loc += a;
    }
    pgsum[pg][k] = asum_loc;
    __syncthreads();
    if (tid < K_) {
        pa[((size_t)n * 125 + chunk) * K_ + tid] =
            pgsum[0][tid] + pgsum[1][tid] + pgsum[2][tid] + pgsum[3][tid];
    }

    const int q = pg;
    float acc[32];
    #pragma unroll
    for (int j = 0; j < 32; ++j) acc[j] = 0.f;
    for (int p = 0; p < 64; p += 4) {
        float a0 = als[p+0][k], a1 = als[p+1][k], a2 = als[p+2][k], a3 = als[p+3][k];
        #pragma unroll
        for (int j = 0; j < 32; ++j) {
            const float4 xv = *(const float4*)&xs[q*32 + j][p];
            acc[j] += a0*xv.x + a1*xv.y + a2*xv.z + a3*xv.w;
        }
    }
    float* pvp = pv + ((((size_t)n * 125 + chunk) * K_ + k) * C_ + q * 32);
    #pragma unroll
    for (int j = 0; j < 32; ++j) pvp[j] = acc[j];
}

__global__ void k_vlad_reduce(const float* __restrict__ pv, float* __restrict__ vlad_raw)
{
    int idx = blockIdx.x * blockDim.x + threadIdx.x;
    if (idx >= NB * 8192) return;
    int n = idx >> 13;
    int rest = idx & 8191;
    const float* p = pv + (size_t)n * 125 * 8192 + rest;
    float s = 0.f;
    for (int ch = 0; ch < 125; ++ch) s += p[(size_t)ch * 8192];
    vlad_raw[(size_t)n * 8192 + rest] = s;
}

__global__ void k_asum_reduce(const float* __restrict__ pa, float* __restrict__ asum)
{
    int idx = blockIdx.x * blockDim.x + threadIdx.x;
    if (idx >= NB * K_) return;
    const float* p = pa + (size_t)(idx >> 6) * 125 * K_ + (idx & 63);
    float s = 0.f;
    for (int ch = 0; ch < 125; ++ch) s += p[ch * K_];
    asum[idx] = s;
}

__global__ __launch_bounds__(128) void k_vlad_finalize(
    const float* __restrict__ vlad_raw, const float* __restrict__ asum,
    const float* __restrict__ centers, float* __restrict__ feat)
{
    __shared__ float red[2];
    const int k = blockIdx.x, n = blockIdx.y, c = threadIdx.x;
    float v = vlad_raw[((size_t)n * K_ + k) * C_ + c] - asum[n * K_ + k] * centers[k * C_ + c];
    float ss = v * v;
    for (int d = 32; d >= 1; d >>= 1) ss += __shfl_xor(ss, d);
    if ((threadIdx.x & 63) == 0) red[threadIdx.x >> 6] = ss;
    __syncthreads();
    float denom = fmaxf(sqrtf(red[0] + red[1]), 1e-12f);
    feat[(size_t)n * 9216 + k * C_ + c] = v / denom;
}

// ======================= max pool, channel-last bf16, 8ch/thread =======================
__global__ void k_maxpool_cl(const ushort* __restrict__ in, ushort* __restrict__ out,
                             int Hi, int Wi, int C8, int ph, int pw, int total)
{
    int idx = blockIdx.x * blockDim.x + threadIdx.x;
    if (idx >= total) return;
    const int Ho = Hi / ph, Wo = Wi / pw;
    const int C = C8 << 3;
    int c8 = idx % C8;
    int t  = idx / C8;
    int wo = t % Wo; t /= Wo;
    int ho = t % Ho;
    int n  = t / Ho;
    const ushort* base = in + ((size_t)(n * Hi + ho * ph) * Wi + wo * pw) * C + (c8 << 3);
    float m[8];
    #pragma unroll
    for (int j = 0; j < 8; ++j) m[j] = -INFINITY;
    for (int r = 0; r < ph; ++r)
        for (int s = 0; s < pw; ++s) {
            s16x8 v = *(const s16x8*)(base + ((size_t)r * Wi + s) * C);
            #pragma unroll
            for (int j = 0; j < 8; ++j) m[j] = fmaxf(m[j], bf2f((ushort)v[j]));
        }
    s16x8 o;
    #pragma unroll
    for (int j = 0; j < 8; ++j) o[j] = f2bf(m[j]);
    *(s16x8*)(out + ((size_t)(n * Ho + ho) * Wo + wo) * C + (c8 << 3)) = o;
}

// conv3 split-K(4) reduce + bias + global 5x25 max pool -> feat[:, 8192:9216]
__global__ void k_pool3_feat(const float* __restrict__ part, const float* __restrict__ bias,
                             float* __restrict__ feat)
{
    int idx = blockIdx.x * blockDim.x + threadIdx.x;   // n*1024 + c
    if (idx >= NB * 1024) return;
    int n = idx >> 10, c = idx & 1023;
    const size_t kstride = (size_t)NB * 1024 * 125;
    const float* p = part + ((size_t)n * 1024 + c) * 125;
    const float b = bias[c];
    float m = -INFINITY;
    for (int i = 0; i < 125; ++i) {
        float s = 0.f;
        #pragma unroll
        for (int ksl = 0; ksl < 4; ++ksl) s += p[i + ksl * kstride];
        m = fmaxf(m, b + s);
    }
    feat[(size_t)n * 9216 + 8192 + c] = m;
}

// ======================= MLP: featnorm -> sliced partial GEMV -> reduce+norm =======================
__global__ __launch_bounds__(256) void k_featnorm(const float* __restrict__ feat,
                                                  float* __restrict__ scale)
{
    __shared__ float r1s[4], r2s[4];
    const int n = blockIdx.x;
    const int tid = threadIdx.x;
    const int wid = tid >> 6;
    float s1 = 0.f, s2 = 0.f;
    const float* f = feat + (size_t)n * 9216;
    for (int i = tid; i < 9216; i += 256) {
        float v = f[i];
        if (i < 8192) s1 += v * v; else s2 += v * v;
    }
    for (int d = 32; d >= 1; d >>= 1) { s1 += __shfl_xor(s1, d); s2 += __shfl_xor(s2, d); }
    if ((tid & 63) == 0) { r1s[wid] = s1; r2s[wid] = s2; }
    __syncthreads();
    if (tid == 0) {
        scale[n * 2 + 0] = 1.f / fmaxf(sqrtf(r1s[0] + r1s[1] + r1s[2] + r1s[3]), 1e-12f);
        scale[n * 2 + 1] = 1.f / fmaxf(sqrtf(r2s[0] + r2s[1] + r2s[2] + r2s[3]), 1e-12f);
    }
}

__global__ __launch_bounds__(256) void k_mlp_part(
    const float* __restrict__ feat, const float* __restrict__ scale,
    const float* __restrict__ wt,   // [9216][256]
    float* __restrict__ part)       // [N][16][256]
{
    __shared__ float fs[576];
    const int n  = blockIdx.x >> 4;
    const int sl = blockIdx.x & 15;
    const int tid = threadIdx.x;
    const int base = sl * 576;
    for (int j = tid; j < 576; j += 256) {
        int idx = base + j;
        fs[j] = feat[(size_t)n * 9216 + idx] * scale[n * 2 + (idx < 8192 ? 0 : 1)];
    }
    __syncthreads();
    float a0 = 0.f, a1 = 0.f;
    for (int j = 0; j < 576; j += 2) {
        a0 += fs[j]     * wt[(size_t)(base + j)     * 256 + tid];
        a1 += fs[j + 1] * wt[(size_t)(base + j + 1) * 256 + tid];
    }
    part[((size_t)n * 16 + sl) * 256 + tid] = a0 + a1;
}

__global__ __launch_bounds__(256) void k_mlp_final(
    const float* __restrict__ part, const float* __restrict__ bias,
    float* __restrict__ outp)
{
    __shared__ float red[4];
    const int n = blockIdx.x;
    const int tid = threadIdx.x;
    float a = bias[tid];
    #pragma unroll
    for (int s = 0; s < 16; ++s) a += part[((size_t)n * 16 + s) * 256 + tid];
    float ss = a * a;
    for (int d = 32; d >= 1; d >>= 1) ss += __shfl_xor(ss, d);
    if ((tid & 63) == 0) red[tid >> 6] = ss;
    __syncthreads();
    const float inv = 1.f / fmaxf(sqrtf(red[0] + red[1] + red[2] + red[3]), 1e-12f);
    outp[n * 256 + tid] = a * inv;
}

// ======================= host launch =======================
extern "C" void kernel_launch(void* const* d_in, const int* in_sizes, int n_in,
                              void* d_out, int out_size, void* d_ws, size_t ws_size,
                              hipStream_t stream)
{
    const float* x      = (const float*)d_in[0];
    const float* cents  = (const float*)d_in[1];
    const float* conv_w = (const float*)d_in[2];
    const float* conv_b = (const float*)d_in[3];
    const float* w1     = (const float*)d_in[4];
    const float* b1     = (const float*)d_in[5];
    const float* w2     = (const float*)d_in[6];
    const float* b2     = (const float*)d_in[7];
    const float* w3     = (const float*)d_in[8];
    const float* b3     = (const float*)d_in[9];
    const float* mlp_w  = (const float*)d_in[10];
    const float* mlp_b  = (const float*)d_in[11];
    float* outp = (float*)d_out;

    char* ws = (char*)d_ws;
    size_t off = 0;
    auto alloc = [&](size_t bytes) -> void* {
        off = (off + 255) & ~(size_t)255;
        void* p = ws + off;
        off += bytes;
        return p;
    };
    ushort* zguard  = (ushort*)alloc(256);
    float*  convw_t = (float*)alloc((size_t)64 * 128 * 4);
    float*  mwt     = (float*)alloc((size_t)9216 * 256 * 4);
    short*  wb1     = (short*)alloc((size_t)819200 * 2);
    short*  wb2     = (short*)alloc((size_t)3276800 * 2);
    short*  wb3     = (short*)alloc((size_t)13107200 * 2);
    ushort* x_cl    = (ushort*)alloc((size_t)NB * 8000 * 128 * 2);      // 32.8 MB
    float*  vlad_raw= (float*)alloc((size_t)NB * 8192 * 4);
    float*  asum    = (float*)alloc((size_t)NB * K_ * 4);
    float*  feat    = (float*)alloc((size_t)NB * 9216 * 4);
    float*  pa      = (float*)alloc((size_t)NB * 125 * K_ * 4);
    float*  scale   = (float*)alloc((size_t)NB * 2 * 4);
    float*  mpart   = (float*)alloc((size_t)NB * 16 * 256 * 4);
    ushort* pool2b  = (ushort*)alloc((size_t)NB * 125 * 512 * 2);       // [n][5][25][512]
    char*   slabA   = (char*)alloc((size_t)8 * NB * 1024 * 125 * 4);    // 65.5 MB multi-use:
                                                                        //  vlad pv f32 / conv outs bf16 / conv3 part f32
    ushort* slabB   = (ushort*)alloc((size_t)NB * 2000 * 256 * 2);      // 16.4 MB pool1 out

    hipMemsetAsync(zguard, 0, 256, stream);

    // ---- one-time prep ----
    {
        dim3 blk(32, 8);
        k_transpose_tiled<<<dim3(4, 2), blk, 0, stream>>>(conv_w, convw_t, 64, 128);
        k_transpose_tiled<<<dim3(288, 8), blk, 0, stream>>>(mlp_w, mwt, 256, 9216);
        k_wprep<<<(819200 + 255) / 256, 256, 0, stream>>>(w1, wb1, 256, 128, 819200);
        k_wprep<<<(3276800 + 255) / 256, 256, 0, stream>>>(w2, wb2, 512, 256, 3276800);
        k_wprep<<<(13107200 + 255) / 256, 256, 0, stream>>>(w3, wb3, 1024, 512, 13107200);
        k_nchw_to_nhwc<<<dim3(250, 4, NB), blk, 0, stream>>>(x, x_cl, 128, 8000);
    }

    // ---- VLAD branch (pv in slabA, consumed before conv1 writes it) ----
    k_vlad_partial<<<dim3(125, NB), 256, 0, stream>>>(x, convw_t, conv_b, (float*)slabA, pa);
    k_vlad_reduce<<<(NB * 8192 + 255) / 256, 256, 0, stream>>>((float*)slabA, vlad_raw);
    k_asum_reduce<<<(NB * K_ + 255) / 256, 256, 0, stream>>>(pa, asum);
    k_vlad_finalize<<<dim3(K_, NB), 128, 0, stream>>>(vlad_raw, asum, cents, feat);

    // ---- conv1: 256co x 64pos (2r x 32c); 2240 blocks = 140pos x 1co x 16n; LDS 14.3KB ----
    k_conv_mfma<6, 36, 2, 2, 0><<<2240, 256, 0, stream>>>(
        x_cl, (const s16x8*)wb1, b1, (ushort*)slabA, nullptr, zguard,
        128, 256, 40, 200, /*WT=*/7, 1, /*nck=*/4, /*xpc=*/8, /*PT=*/140);
    {
        int tot = NB * 20 * 100 * 32;   // C8 = 32
        k_maxpool_cl<<<(tot + 255) / 256, 256, 0, stream>>>(
            (ushort*)slabA, slabB, 40, 200, 32, 2, 2, tot);
    }
    // ---- conv2: 256co x 64pos (2r x 32c); 1280 blocks = 40pos x 2co x 16n ----
    k_conv_mfma<6, 36, 2, 2, 0><<<1280, 256, 0, stream>>>(
        slabB, (const s16x8*)wb2, b2, (ushort*)slabA, nullptr, zguard,
        256, 512, 20, 100, /*WT=*/4, 1, /*nck=*/8, /*xpc=*/4, /*PT=*/40);
    {
        int tot = NB * 5 * 25 * 64;     // C8 = 64
        k_maxpool_cl<<<(tot + 255) / 256, 256, 0, stream>>>(
            (ushort*)slabA, pool2b, 20, 100, 64, 4, 4, tot);
    }
    // ---- conv3: 256co x 64pos halves, split-K x4; 512 blocks = 2pos x 4ks x 4co x 16n ----
    k_conv_mfma<9, 29, 2, 2, 1><<<512, 256, 0, stream>>>(
        pool2b, (const s16x8*)wb3, b3, nullptr, (float*)slabA, zguard,
        512, 1024, 5, 25, /*WT=*/1, 0, /*nck=*/4, /*xpc=*/2, /*PT=*/8);
    // ---- split-K(4) reduce + bias + 5x25 max pool -> feat[:, 8192:] ----
    k_pool3_feat<<<(NB * 1024 + 255) / 256, 256, 0, stream>>>((float*)slabA, b3, feat);

    // ---- norms + MLP + final norm ----
    k_featnorm<<<NB, 256, 0, stream>>>(feat, scale);
    k_mlp_part<<<NB * 16, 256, 0, stream>>>(feat, scale, mwt, mpart);
    k_mlp_final<<<NB, 256, 0, stream>>>(mpart, mlp_b, outp);
}

// Round 12
// 1093.644 us; speedup vs baseline: 1.7082x; 1.7082x over previous
//
#include <hip/hip_runtime.h>
#include <math.h>

#define K_ 64
#define C_ 128
#define NB 16
#define P_ 8000

typedef float f32x4 __attribute__((ext_vector_type(4)));
typedef short s16x8 __attribute__((ext_vector_type(8)));

__device__ __forceinline__ short f2bf(float v) {
    unsigned u = __float_as_uint(v);
    u += 0x7FFFu + ((u >> 16) & 1u);
    return (short)(u >> 16);
}
__device__ __forceinline__ float bf2f(ushort u) { return __uint_as_float(((unsigned)u) << 16); }

// async global->LDS 16B DMA; dest is wave-uniform base + lane*16
__device__ __forceinline__ void stage16(const void* g, void* l) {
    __builtin_amdgcn_global_load_lds(
        (const __attribute__((address_space(1))) void*)g,
        (__attribute__((address_space(3))) void*)l, 16, 0, 0);
}

// ======================= tiled transpose: in[Co][E] -> out[E][Co] (f32) =======================
__global__ void k_transpose_tiled(const float* __restrict__ in, float* __restrict__ out,
                                  int Co, int E)
{
    __shared__ float t[32][33];
    const int e0  = blockIdx.x * 32;
    const int co0 = blockIdx.y * 32;
    for (int i = threadIdx.y; i < 32; i += 8) {
        int co = co0 + i, e = e0 + threadIdx.x;
        t[i][threadIdx.x] = (co < Co && e < E) ? in[(size_t)co * E + e] : 0.f;
    }
    __syncthreads();
    for (int i = threadIdx.y; i < 32; i += 8) {
        int e = e0 + i, co = co0 + threadIdx.x;
        if (e < E && co < Co) out[(size_t)e * Co + co] = t[threadIdx.x][i];
    }
}

// ======================= NCHW f32 -> NHWC bf16 =======================
__global__ void k_nchw_to_nhwc(const float* __restrict__ in, ushort* __restrict__ out,
                               int C, int P)
{
    __shared__ ushort t[32][33];
    const int n  = blockIdx.z;
    const int p0 = blockIdx.x * 32;
    const int c0 = blockIdx.y * 32;
    for (int i = threadIdx.y; i < 32; i += 8) {
        int c = c0 + i, p = p0 + threadIdx.x;
        t[i][threadIdx.x] = (c < C && p < P) ? (ushort)f2bf(in[((size_t)n * C + c) * P + p]) : 0;
    }
    __syncthreads();
    for (int i = threadIdx.y; i < 32; i += 8) {
        int p = p0 + i, c = c0 + threadIdx.x;
        if (p < P && c < C) out[((size_t)n * P + p) * C + c] = t[threadIdx.x][i];
    }
}

// ======================= weight prep: w[Co][Cin][5][5] f32 -> wb[((ck*25+t)*Co+co)*32+cl] bf16 ====
__global__ void k_wprep(const float* __restrict__ w, short* __restrict__ wb,
                        int Co, int Cin, int total)
{
    int idx = blockIdx.x * blockDim.x + threadIdx.x;
    if (idx >= total) return;
    int cl = idx & 31;
    int rest = idx >> 5;
    int co = rest % Co;
    int rest2 = rest / Co;
    int t = rest2 % 25;
    int ck = rest2 / 25;
    float v = w[((size_t)co * Cin + (ck << 5) + cl) * 25 + t];
    wb[idx] = f2bf(v);
}

// ======================= implicit-GEMM conv 5x5 pad 2, bf16 MFMA, channel-last in/out ==========
// block: 256 thr = 4 waves, EACH OWNING A DISTINCT 64-co SLICE. block tile: 256co x 128pos.
// Weights: per-wave private 3-deep LDS ring (4KB/slot/wave, unique data), DMA'd TWO taps ahead,
// per-wave counted vmcnt(8) (tail: 4/0) -- NO barriers inside a chunk. 2 barriers per chunk for
// the shared input tile. Tap loop fully unrolled; s_setprio(1) around the MFMA cluster.
template<int SR, int NC, int WR, int WC16, int IS3>
__global__ __launch_bounds__(256) void k_conv_mfma(
    const ushort* __restrict__ in, const s16x8* __restrict__ wb,
    const float* __restrict__ bias, ushort* __restrict__ outb, float* __restrict__ outf,
    const ushort* __restrict__ zg,
    int Cin, int Co, int H, int W, int WT, int leaky, int nck, int xpc, int PT)
{
    constexpr int NT   = IS3 ? 8 : (WR * WC16);
    constexpr int TOT  = SR * NC * 4;
    constexpr int TOTP = (TOT + 63) & ~63;
    __shared__ s16x8 xin[TOTP];
    __shared__ s16x8 wl[3][4][256];   // [ring slot][wave][4KB private weight tile, unique]

    const int tid  = threadIdx.x;
    const int lane = tid & 63;
    const int wid  = tid >> 6;
    const int wm   = wid;             // wave's co slice
    const int n16  = lane & 15;
    const int g    = lane >> 4;

    // XCD-aware decode: co-blocks partitioned across XCDs -> per-XCD weight set fits L2
    const int lid  = blockIdx.x;
    const int xcd  = lid & 7;
    const int rrr  = lid >> 3;
    const int co_blk = xcd / xpc;
    const int posn = rrr * xpc + (xcd % xpc);
    const int n    = posn / PT;
    const int bx   = posn % PT;

    const int h0  = IS3 ? 0 : (bx / WT) * WR;
    const int w0  = IS3 ? 0 : (bx % WT) * (WC16 * 16);
    const int ks  = IS3 ? bx : 0;
    const int co0 = co_blk * 256;

    int ph[NT], pw[NT];
    if (IS3) {
        #pragma unroll
        for (int nt = 0; nt < NT; ++nt) {
            int pos = nt * 16 + n16;
            int h = pos / 25;
            int w = pos - h * 25;
            if (h > 4) { h = 0; w = 0; }
            ph[nt] = h; pw[nt] = w;
        }
    }

    f32x4 acc[4][NT];
    #pragma unroll
    for (int i = 0; i < 4; ++i)
        #pragma unroll
        for (int j = 0; j < NT; ++j) acc[i][j] = f32x4{0.f, 0.f, 0.f, 0.f};

    const int ck0 = IS3 ? ks * nck : 0;
    const int ckend = ck0 + nck;

    // stage input chunk ck via async DMA (inverse-swizzled global source, linear LDS dest)
    auto stage_input = [&](int ck) {
        for (int c = wid; c * 64 < TOTP; c += 4) {
            int u = c * 64 + lane;
            int row = u / (NC * 4);
            int rem = u - row * (NC * 4);
            int col = rem >> 2;
            int s   = rem & 3;
            int g8  = (s - (col >> 1) - row) & 3;
            int gh = h0 + row - 2, gw = w0 + col - 2;
            const void* src =
                (u < TOT && (unsigned)gh < (unsigned)H && (unsigned)gw < (unsigned)W)
                ? (const void*)(in + ((size_t)(n * H + gh) * W + gw) * Cin + (ck << 5) + (g8 << 3))
                : (const void*)zg;
            stage16(src, (void*)&xin[c * 64]);
        }
    };
    // stage THIS WAVE's unique 4KB weight slice for global tap gT into private ring slot
    auto stage_w = [&](int gT, int slot) {
        const s16x8* src = wb + ((size_t)gT * Co + co0 + wm * 64) * 4 + lane;
        #pragma unroll
        for (int k = 0; k < 4; ++k)
            stage16((const void*)(src + k * 64), (void*)&wl[slot][wid][k * 64]);
    };

    for (int ck = ck0; ck < ckend; ++ck) {
        if (ck != ck0) __builtin_amdgcn_s_barrier();   // all waves done reading old xin
        stage_input(ck);
        stage_w(ck * 25 + 0, 0);
        stage_w(ck * 25 + 1, 1);
        // drain own input DMAs + W0 (older); leave W1's 4 in flight
        asm volatile("s_waitcnt vmcnt(4)" ::: "memory");
        __builtin_amdgcn_sched_barrier(0);
        __builtin_amdgcn_s_barrier();                  // all waves' input slices landed

        #pragma unroll
        for (int t = 0; t < 25; ++t) {
            if (t < 23) {
                stage_w(ck * 25 + t + 2, (t + 2) % 3);
                asm volatile("s_waitcnt vmcnt(8)" ::: "memory");  // W[t] done; W[t+1],W[t+2] in flight
            } else if (t == 23) {
                asm volatile("s_waitcnt vmcnt(4)" ::: "memory");  // W[23] done; W[24] in flight
            } else {
                asm volatile("s_waitcnt vmcnt(0)" ::: "memory");  // tail: drain all
            }
            __builtin_amdgcn_sched_barrier(0);

            const int r = t / 5, s = t - (t / 5) * 5;

            // ---- A-fragments from private ring slot (own wave's unique slice) ----
            const s16x8* wt_ = &wl[t % 3][wid][n16 * 4 + g];
            s16x8 wf[4];
            #pragma unroll
            for (int mt = 0; mt < 4; ++mt) wf[mt] = wt_[mt * 64];

            // ---- B-fragments from shared input tile ----
            s16x8 bf[NT];
            #pragma unroll
            for (int nt = 0; nt < NT; ++nt) {
                int row, col;
                if (IS3) { row = ph[nt] + r; col = pw[nt] + s; }
                else {
                    int rr = nt / WC16, cc = nt - rr * WC16;
                    row = rr + r;
                    col = cc * 16 + n16 + s;
                }
                bf[nt] = xin[(row * NC + col) * 4 + ((g + (col >> 1) + row) & 3)];
            }
            __builtin_amdgcn_s_setprio(1);
            #pragma unroll
            for (int mt = 0; mt < 4; ++mt)
                #pragma unroll
                for (int nt = 0; nt < NT; ++nt)
                    acc[mt][nt] = __builtin_amdgcn_mfma_f32_16x16x32_bf16(
                        wf[mt], bf[nt], acc[mt][nt], 0, 0, 0);
            __builtin_amdgcn_s_setprio(0);
        }
    }

    // ---- epilogue: C/D layout col=lane&15 (pos), row=g*4+reg (co) ----
    if (IS3) {
        #pragma unroll
        for (int mt = 0; mt < 4; ++mt) {
            #pragma unroll
            for (int reg = 0; reg < 4; ++reg) {
                const int co = co0 + wm * 64 + mt * 16 + g * 4 + reg;
                #pragma unroll
                for (int nt = 0; nt < NT; ++nt) {
                    int pos = nt * 16 + n16;
                    if (pos < 125)
                        outf[((size_t)(ks * NB + n) * Co + co) * 125 + pos] = acc[mt][nt][reg];
                }
            }
        }
    } else {
        #pragma unroll
        for (int mt = 0; mt < 4; ++mt) {
            const int cobase = co0 + wm * 64 + mt * 16 + g * 4;
            const float b0 = bias[cobase + 0];
            const float b1 = bias[cobase + 1];
            const float b2 = bias[cobase + 2];
            const float b3 = bias[cobase + 3];
            #pragma unroll
            for (int nt = 0; nt < NT; ++nt) {
                int rr = nt / WC16, cc = nt - rr * WC16;
                int h  = h0 + rr;
                int wp = w0 + cc * 16 + n16;
                if (h < H && wp < W) {
                    float v0 = acc[mt][nt][0] + b0;
                    float v1 = acc[mt][nt][1] + b1;
                    float v2 = acc[mt][nt][2] + b2;
                    float v3 = acc[mt][nt][3] + b3;
                    if (leaky) {
                        v0 = (v0 >= 0.f) ? v0 : 0.2f * v0;
                        v1 = (v1 >= 0.f) ? v1 : 0.2f * v1;
                        v2 = (v2 >= 0.f) ? v2 : 0.2f * v2;
                        v3 = (v3 >= 0.f) ? v3 : 0.2f * v3;
                    }
                    ushort4 pkd;
                    pkd.x = (ushort)f2bf(v0);
                    pkd.y = (ushort)f2bf(v1);
                    pkd.z = (ushort)f2bf(v2);
                    pkd.w = (ushort)f2bf(v3);
                    *(ushort4*)(outb + ((size_t)(n * H + h) * W + wp) * Co + cobase) = pkd;
                }
            }
        }
    }
}

// ======================= VLAD partial: softmax assignment + partial einsum =======================
__global__ __launch_bounds__(256) void k_vlad_partial(
    const float* __restrict__ x,        // [N][C][P]
    const float* __restrict__ convw_t,  // [C][K]
    const float* __restrict__ convb,    // [K]
    float* __restrict__ pv,             // [N][125][K][C]
    float* __restrict__ pa)             // [N][125][K]
{
    __shared__ float xs[C_][64];
    __shared__ float als[64][K_];
    __shared__ float pgsum[4][K_];

    const int tid = threadIdx.x;
    const int chunk = blockIdx.x;    // 0..124
    const int n = blockIdx.y;        // 0..15
    const int p0 = chunk * 64;

    const float* xn = x + (size_t)n * C_ * P_ + p0;
    for (int i = tid; i < C_ * 64; i += 256) {
        int c = i >> 6, pp = i & 63;
        xs[c][pp] = xn[(size_t)c * P_ + pp];
    }
    __syncthreads();

    const int k  = tid & 63;
    const int pg = tid >> 6;

    float sa[16];
    const float bk = convb[k];
    #pragma unroll
    for (int j = 0; j < 16; ++j) sa[j] = bk;
    for (int c = 0; c < C_; ++c) {
        float wv = convw_t[c * K_ + k];
        const float4* xp = (const float4*)&xs[c][pg * 16];
        #pragma unroll
        for (int q = 0; q < 4; ++q) {
            float4 xv = xp[q];
            sa[q*4+0] += wv * xv.x;
            sa[q*4+1] += wv * xv.y;
            sa[q*4+2] += wv * xv.z;
            sa[q*4+3] += wv * xv.w;
        }
    }

    float asum_loc = 0.f;
    #pragma unroll
    for (int j = 0; j < 16; ++j) {
        float m = sa[j];
        for (int d = 32; d >= 1; d >>= 1) m = fmaxf(m, __shfl_xor(m, d));
        float e = __expf(sa[j] - m);
        float s = e;
        for (int d = 32; d >= 1; d >>= 1) s += __shfl_xor(s, d);
        float a = e / s;
        als[pg * 16 + j][k] = a;
        asum_loc += a;
    }
    pgsum[pg][k] = asum_loc;
    __syncthreads();
    if (tid < K_) {
        pa[((size_t)n * 125 + chunk) * K_ + tid] =
            pgsum[0][tid] + pgsum[1][tid] + pgsum[2][tid] + pgsum[3][tid];
    }

    const int q = pg;
    float acc[32];
    #pragma unroll
    for (int j = 0; j < 32; ++j) acc[j] = 0.f;
    for (int p = 0; p < 64; p += 4) {
        float a0 = als[p+0][k], a1 = als[p+1][k], a2 = als[p+2][k], a3 = als[p+3][k];
        #pragma unroll
        for (int j = 0; j < 32; ++j) {
            const float4 xv = *(const float4*)&xs[q*32 + j][p];
            acc[j] += a0*xv.x + a1*xv.y + a2*xv.z + a3*xv.w;
        }
    }
    float* pvp = pv + ((((size_t)n * 125 + chunk) * K_ + k) * C_ + q * 32);
    #pragma unroll
    for (int j = 0; j < 32; ++j) pvp[j] = acc[j];
}

__global__ void k_vlad_reduce(const float* __restrict__ pv, float* __restrict__ vlad_raw)
{
    int idx = blockIdx.x * blockDim.x + threadIdx.x;
    if (idx >= NB * 8192) return;
    int n = idx >> 13;
    int rest = idx & 8191;
    const float* p = pv + (size_t)n * 125 * 8192 + rest;
    float s = 0.f;
    for (int ch = 0; ch < 125; ++ch) s += p[(size_t)ch * 8192];
    vlad_raw[(size_t)n * 8192 + rest] = s;
}

__global__ void k_asum_reduce(const float* __restrict__ pa, float* __restrict__ asum)
{
    int idx = blockIdx.x * blockDim.x + threadIdx.x;
    if (idx >= NB * K_) return;
    const float* p = pa + (size_t)(idx >> 6) * 125 * K_ + (idx & 63);
    float s = 0.f;
    for (int ch = 0; ch < 125; ++ch) s += p[ch * K_];
    asum[idx] = s;
}

__global__ __launch_bounds__(128) void k_vlad_finalize(
    const float* __restrict__ vlad_raw, const float* __restrict__ asum,
    const float* __restrict__ centers, float* __restrict__ feat)
{
    __shared__ float red[2];
    const int k = blockIdx.x, n = blockIdx.y, c = threadIdx.x;
    float v = vlad_raw[((size_t)n * K_ + k) * C_ + c] - asum[n * K_ + k] * centers[k * C_ + c];
    float ss = v * v;
    for (int d = 32; d >= 1; d >>= 1) ss += __shfl_xor(ss, d);
    if ((threadIdx.x & 63) == 0) red[threadIdx.x >> 6] = ss;
    __syncthreads();
    float denom = fmaxf(sqrtf(red[0] + red[1]), 1e-12f);
    feat[(size_t)n * 9216 + k * C_ + c] = v / denom;
}

// ======================= max pool, channel-last bf16, 8ch/thread =======================
__global__ void k_maxpool_cl(const ushort* __restrict__ in, ushort* __restrict__ out,
                             int Hi, int Wi, int C8, int ph, int pw, int total)
{
    int idx = blockIdx.x * blockDim.x + threadIdx.x;
    if (idx >= total) return;
    const int Ho = Hi / ph, Wo = Wi / pw;
    const int C = C8 << 3;
    int c8 = idx % C8;
    int t  = idx / C8;
    int wo = t % Wo; t /= Wo;
    int ho = t % Ho;
    int n  = t / Ho;
    const ushort* base = in + ((size_t)(n * Hi + ho * ph) * Wi + wo * pw) * C + (c8 << 3);
    float m[8];
    #pragma unroll
    for (int j = 0; j < 8; ++j) m[j] = -INFINITY;
    for (int r = 0; r < ph; ++r)
        for (int s = 0; s < pw; ++s) {
            s16x8 v = *(const s16x8*)(base + ((size_t)r * Wi + s) * C);
            #pragma unroll
            for (int j = 0; j < 8; ++j) m[j] = fmaxf(m[j], bf2f((ushort)v[j]));
        }
    s16x8 o;
    #pragma unroll
    for (int j = 0; j < 8; ++j) o[j] = f2bf(m[j]);
    *(s16x8*)(out + ((size_t)(n * Ho + ho) * Wo + wo) * C + (c8 << 3)) = o;
}

// conv3 split-K(8) reduce + bias + global 5x25 max pool -> feat[:, 8192:9216]
__global__ void k_pool3_feat(const float* __restrict__ part, const float* __restrict__ bias,
                             float* __restrict__ feat)
{
    int idx = blockIdx.x * blockDim.x + threadIdx.x;   // n*1024 + c
    if (idx >= NB * 1024) return;
    int n = idx >> 10, c = idx & 1023;
    const size_t kstride = (size_t)NB * 1024 * 125;
    const float* p = part + ((size_t)n * 1024 + c) * 125;
    const float b = bias[c];
    float m = -INFINITY;
    for (int i = 0; i < 125; ++i) {
        float s = 0.f;
        #pragma unroll
        for (int ksl = 0; ksl < 8; ++ksl) s += p[i + ksl * kstride];
        m = fmaxf(m, b + s);
    }
    feat[(size_t)n * 9216 + 8192 + c] = m;
}

// ======================= MLP: featnorm -> sliced partial GEMV -> reduce+norm =======================
__global__ __launch_bounds__(256) void k_featnorm(const float* __restrict__ feat,
                                                  float* __restrict__ scale)
{
    __shared__ float r1s[4], r2s[4];
    const int n = blockIdx.x;
    const int tid = threadIdx.x;
    const int wid = tid >> 6;
    float s1 = 0.f, s2 = 0.f;
    const float* f = feat + (size_t)n * 9216;
    for (int i = tid; i < 9216; i += 256) {
        float v = f[i];
        if (i < 8192) s1 += v * v; else s2 += v * v;
    }
    for (int d = 32; d >= 1; d >>= 1) { s1 += __shfl_xor(s1, d); s2 += __shfl_xor(s2, d); }
    if ((tid & 63) == 0) { r1s[wid] = s1; r2s[wid] = s2; }
    __syncthreads();
    if (tid == 0) {
        scale[n * 2 + 0] = 1.f / fmaxf(sqrtf(r1s[0] + r1s[1] + r1s[2] + r1s[3]), 1e-12f);
        scale[n * 2 + 1] = 1.f / fmaxf(sqrtf(r2s[0] + r2s[1] + r2s[2] + r2s[3]), 1e-12f);
    }
}

__global__ __launch_bounds__(256) void k_mlp_part(
    const float* __restrict__ feat, const float* __restrict__ scale,
    const float* __restrict__ wt,   // [9216][256]
    float* __restrict__ part)       // [N][16][256]
{
    __shared__ float fs[576];
    const int n  = blockIdx.x >> 4;
    const int sl = blockIdx.x & 15;
    const int tid = threadIdx.x;
    const int base = sl * 576;
    for (int j = tid; j < 576; j += 256) {
        int idx = base + j;
        fs[j] = feat[(size_t)n * 9216 + idx] * scale[n * 2 + (idx < 8192 ? 0 : 1)];
    }
    __syncthreads();
    float a0 = 0.f, a1 = 0.f;
    for (int j = 0; j < 576; j += 2) {
        a0 += fs[j]     * wt[(size_t)(base + j)     * 256 + tid];
        a1 += fs[j + 1] * wt[(size_t)(base + j + 1) * 256 + tid];
    }
    part[((size_t)n * 16 + sl) * 256 + tid] = a0 + a1;
}

__global__ __launch_bounds__(256) void k_mlp_final(
    const float* __restrict__ part, const float* __restrict__ bias,
    float* __restrict__ outp)
{
    __shared__ float red[4];
    const int n = blockIdx.x;
    const int tid = threadIdx.x;
    float a = bias[tid];
    #pragma unroll
    for (int s = 0; s < 16; ++s) a += part[((size_t)n * 16 + s) * 256 + tid];
    float ss = a * a;
    for (int d = 32; d >= 1; d >>= 1) ss += __shfl_xor(ss, d);
    if ((tid & 63) == 0) red[tid >> 6] = ss;
    __syncthreads();
    const float inv = 1.f / fmaxf(sqrtf(red[0] + red[1] + red[2] + red[3]), 1e-12f);
    outp[n * 256 + tid] = a * inv;
}

// ======================= host launch =======================
extern "C" void kernel_launch(void* const* d_in, const int* in_sizes, int n_in,
                              void* d_out, int out_size, void* d_ws, size_t ws_size,
                              hipStream_t stream)
{
    const float* x      = (const float*)d_in[0];
    const float* cents  = (const float*)d_in[1];
    const float* conv_w = (const float*)d_in[2];
    const float* conv_b = (const float*)d_in[3];
    const float* w1     = (const float*)d_in[4];
    const float* b1     = (const float*)d_in[5];
    const float* w2     = (const float*)d_in[6];
    const float* b2     = (const float*)d_in[7];
    const float* w3     = (const float*)d_in[8];
    const float* b3     = (const float*)d_in[9];
    const float* mlp_w  = (const float*)d_in[10];
    const float* mlp_b  = (const float*)d_in[11];
    float* outp = (float*)d_out;

    char* ws = (char*)d_ws;
    size_t off = 0;
    auto alloc = [&](size_t bytes) -> void* {
        off = (off + 255) & ~(size_t)255;
        void* p = ws + off;
        off += bytes;
        return p;
    };
    ushort* zguard  = (ushort*)alloc(256);
    float*  convw_t = (float*)alloc((size_t)64 * 128 * 4);
    float*  mwt     = (float*)alloc((size_t)9216 * 256 * 4);
    short*  wb1     = (short*)alloc((size_t)819200 * 2);
    short*  wb2     = (short*)alloc((size_t)3276800 * 2);
    short*  wb3     = (short*)alloc((size_t)13107200 * 2);
    ushort* x_cl    = (ushort*)alloc((size_t)NB * 8000 * 128 * 2);      // 32.8 MB
    float*  vlad_raw= (float*)alloc((size_t)NB * 8192 * 4);
    float*  asum    = (float*)alloc((size_t)NB * K_ * 4);
    float*  feat    = (float*)alloc((size_t)NB * 9216 * 4);
    float*  pa      = (float*)alloc((size_t)NB * 125 * K_ * 4);
    float*  scale   = (float*)alloc((size_t)NB * 2 * 4);
    float*  mpart   = (float*)alloc((size_t)NB * 16 * 256 * 4);
    ushort* pool2b  = (ushort*)alloc((size_t)NB * 125 * 512 * 2);       // [n][5][25][512]
    char*   slabA   = (char*)alloc((size_t)8 * NB * 1024 * 125 * 4);    // 65.5 MB multi-use:
                                                                        //  vlad pv f32 / conv outs bf16 / conv3 part3 f32
    ushort* slabB   = (ushort*)alloc((size_t)NB * 2000 * 256 * 2);      // 16.4 MB pool1 out

    hipMemsetAsync(zguard, 0, 256, stream);

    // ---- one-time prep ----
    {
        dim3 blk(32, 8);
        k_transpose_tiled<<<dim3(4, 2), blk, 0, stream>>>(conv_w, convw_t, 64, 128);
        k_transpose_tiled<<<dim3(288, 8), blk, 0, stream>>>(mlp_w, mwt, 256, 9216);
        k_wprep<<<(819200 + 255) / 256, 256, 0, stream>>>(w1, wb1, 256, 128, 819200);
        k_wprep<<<(3276800 + 255) / 256, 256, 0, stream>>>(w2, wb2, 512, 256, 3276800);
        k_wprep<<<(13107200 + 255) / 256, 256, 0, stream>>>(w3, wb3, 1024, 512, 13107200);
        k_nchw_to_nhwc<<<dim3(250, 4, NB), blk, 0, stream>>>(x, x_cl, 128, 8000);
    }

    // ---- VLAD branch (pv in slabA, consumed before conv1 writes it) ----
    k_vlad_partial<<<dim3(125, NB), 256, 0, stream>>>(x, convw_t, conv_b, (float*)slabA, pa);
    k_vlad_reduce<<<(NB * 8192 + 255) / 256, 256, 0, stream>>>((float*)slabA, vlad_raw);
    k_asum_reduce<<<(NB * K_ + 255) / 256, 256, 0, stream>>>(pa, asum);
    k_vlad_finalize<<<dim3(K_, NB), 128, 0, stream>>>(vlad_raw, asum, cents, feat);

    // ---- conv1: 256co x 128pos (4r x 32c); 1120 blocks = 70pos x 1co x 16n; LDS 67.6KB ----
    k_conv_mfma<8, 36, 4, 2, 0><<<1120, 256, 0, stream>>>(
        x_cl, (const s16x8*)wb1, b1, (ushort*)slabA, nullptr, zguard,
        128, 256, 40, 200, 7, 1, 4, /*xpc=*/8, /*PT=*/70);
    {
        int tot = NB * 20 * 100 * 32;   // C8 = 32
        k_maxpool_cl<<<(tot + 255) / 256, 256, 0, stream>>>(
            (ushort*)slabA, slabB, 40, 200, 32, 2, 2, tot);
    }
    // ---- conv2: 256co x 128pos (4r x 32c); 640 blocks = 20pos x 2co x 16n; LDS 67.6KB ----
    k_conv_mfma<8, 36, 4, 2, 0><<<640, 256, 0, stream>>>(
        slabB, (const s16x8*)wb2, b2, (ushort*)slabA, nullptr, zguard,
        256, 512, 20, 100, 4, 1, 8, /*xpc=*/4, /*PT=*/20);
    {
        int tot = NB * 5 * 25 * 64;     // C8 = 64
        k_maxpool_cl<<<(tot + 255) / 256, 256, 0, stream>>>(
            (ushort*)slabA, pool2b, 20, 100, 64, 4, 4, tot);
    }
    // ---- conv3: 256co x whole plane, split-K x8; 512 blocks = 8ks x 4co x 16n; part3 = slabA ----
    k_conv_mfma<9, 29, 4, 2, 1><<<512, 256, 0, stream>>>(
        pool2b, (const s16x8*)wb3, b3, nullptr, (float*)slabA, zguard,
        512, 1024, 5, 25, 1, 0, 2, /*xpc=*/2, /*PT=*/8);
    // ---- split-K(8) reduce + bias + 5x25 max pool -> feat[:, 8192:] ----
    k_pool3_feat<<<(NB * 1024 + 255) / 256, 256, 0, stream>>>((float*)slabA, b3, feat);

    // ---- norms + MLP + final norm ----
    k_featnorm<<<NB, 256, 0, stream>>>(feat, scale);
    k_mlp_part<<<NB * 16, 256, 0, stream>>>(feat, scale, mwt, mpart);
    k_mlp_final<<<NB, 256, 0, stream>>>(mpart, mlp_b, outp);
}

// Round 13
// 960.160 us; speedup vs baseline: 1.9457x; 1.1390x over previous
//
#include <hip/hip_runtime.h>
#include <math.h>

#define K_ 64
#define C_ 128
#define NB 16
#define P_ 8000

typedef float f32x4 __attribute__((ext_vector_type(4)));
typedef short s16x8 __attribute__((ext_vector_type(8)));

__device__ __forceinline__ short f2bf(float v) {
    unsigned u = __float_as_uint(v);
    u += 0x7FFFu + ((u >> 16) & 1u);
    return (short)(u >> 16);
}
__device__ __forceinline__ float bf2f(ushort u) { return __uint_as_float(((unsigned)u) << 16); }

// async global->LDS 16B DMA; dest is wave-uniform base + lane*16
__device__ __forceinline__ void stage16(const void* g, void* l) {
    __builtin_amdgcn_global_load_lds(
        (const __attribute__((address_space(1))) void*)g,
        (__attribute__((address_space(3))) void*)l, 16, 0, 0);
}

// ======================= tiled transpose: in[Co][E] -> out[E][Co] (f32) =======================
__global__ void k_transpose_tiled(const float* __restrict__ in, float* __restrict__ out,
                                  int Co, int E)
{
    __shared__ float t[32][33];
    const int e0  = blockIdx.x * 32;
    const int co0 = blockIdx.y * 32;
    for (int i = threadIdx.y; i < 32; i += 8) {
        int co = co0 + i, e = e0 + threadIdx.x;
        t[i][threadIdx.x] = (co < Co && e < E) ? in[(size_t)co * E + e] : 0.f;
    }
    __syncthreads();
    for (int i = threadIdx.y; i < 32; i += 8) {
        int e = e0 + i, co = co0 + threadIdx.x;
        if (e < E && co < Co) out[(size_t)e * Co + co] = t[threadIdx.x][i];
    }
}

// ======================= NCHW f32 -> NHWC bf16 =======================
__global__ void k_nchw_to_nhwc(const float* __restrict__ in, ushort* __restrict__ out,
                               int C, int P)
{
    __shared__ ushort t[32][33];
    const int n  = blockIdx.z;
    const int p0 = blockIdx.x * 32;
    const int c0 = blockIdx.y * 32;
    for (int i = threadIdx.y; i < 32; i += 8) {
        int c = c0 + i, p = p0 + threadIdx.x;
        t[i][threadIdx.x] = (c < C && p < P) ? (ushort)f2bf(in[((size_t)n * C + c) * P + p]) : 0;
    }
    __syncthreads();
    for (int i = threadIdx.y; i < 32; i += 8) {
        int p = p0 + i, c = c0 + threadIdx.x;
        if (p < P && c < C) out[((size_t)n * P + p) * C + c] = t[threadIdx.x][i];
    }
}

// ======================= weight prep: w[Co][Cin][5][5] f32 -> wb[((ck*25+t)*Co+co)*32+cl] bf16 ====
__global__ void k_wprep(const float* __restrict__ w, short* __restrict__ wb,
                        int Co, int Cin, int total)
{
    int idx = blockIdx.x * blockDim.x + threadIdx.x;
    if (idx >= total) return;
    int cl = idx & 31;
    int rest = idx >> 5;
    int co = rest % Co;
    int rest2 = rest / Co;
    int t = rest2 % 25;
    int ck = rest2 / 25;
    float v = w[((size_t)co * Cin + (ck << 5) + cl) * 25 + t];
    wb[idx] = f2bf(v);
}

// ======================= implicit-GEMM conv 5x5 pad 2, bf16 MFMA, channel-last in/out ==========
// block: 256 thr = 4 waves, EACH OWNING A DISTINCT 64-co SLICE. block tile: 256co x 128pos.
// Weights: global -> REGISTERS, 3-slot rotating ring loaded 2 taps ahead (fully unrolled tap
// loop -> static indices; compiler emits counted vmcnt waits). No weight LDS -> no ring
// conflicts, half the LDS traffic. Input: single LDS buffer via global_load_lds, 2 barriers/chunk.
template<int SR, int NC, int WR, int WC16, int IS3>
__global__ __launch_bounds__(256) void k_conv_mfma(
    const ushort* __restrict__ in, const s16x8* __restrict__ wb,
    const float* __restrict__ bias, ushort* __restrict__ outb, float* __restrict__ outf,
    const ushort* __restrict__ zg,
    int Cin, int Co, int H, int W, int WT, int leaky, int nck, int xpc, int PT)
{
    constexpr int NT   = IS3 ? 8 : (WR * WC16);
    constexpr int TOT  = SR * NC * 4;
    constexpr int TOTP = (TOT + 63) & ~63;
    __shared__ s16x8 xin[TOTP];

    const int tid  = threadIdx.x;
    const int lane = tid & 63;
    const int wid  = tid >> 6;
    const int wm   = wid;             // wave's co slice
    const int n16  = lane & 15;
    const int g    = lane >> 4;

    // XCD-aware decode: co-blocks partitioned across XCDs -> per-XCD weight set fits L2
    const int lid  = blockIdx.x;
    const int xcd  = lid & 7;
    const int rrr  = lid >> 3;
    const int co_blk = xcd / xpc;
    const int posn = rrr * xpc + (xcd % xpc);
    const int n    = posn / PT;
    const int bx   = posn % PT;

    const int h0  = IS3 ? 0 : (bx / WT) * WR;
    const int w0  = IS3 ? 0 : (bx % WT) * (WC16 * 16);
    const int ks  = IS3 ? bx : 0;
    const int co0 = co_blk * 256;

    int ph[NT], pw[NT];
    if (IS3) {
        #pragma unroll
        for (int nt = 0; nt < NT; ++nt) {
            int pos = nt * 16 + n16;
            int h = pos / 25;
            int w = pos - h * 25;
            if (h > 4) { h = 0; w = 0; }
            ph[nt] = h; pw[nt] = w;
        }
    }

    f32x4 acc[4][NT];
    #pragma unroll
    for (int i = 0; i < 4; ++i)
        #pragma unroll
        for (int j = 0; j < NT; ++j) acc[i][j] = f32x4{0.f, 0.f, 0.f, 0.f};

    const int ck0 = IS3 ? ks * nck : 0;
    const int ckend = ck0 + nck;

    // stage input chunk ck via async DMA (inverse-swizzled global source, linear LDS dest)
    auto stage_input = [&](int ck) {
        for (int c = wid; c * 64 < TOTP; c += 4) {
            int u = c * 64 + lane;
            int row = u / (NC * 4);
            int rem = u - row * (NC * 4);
            int col = rem >> 2;
            int s   = rem & 3;
            int g8  = (s - (col >> 1) - row) & 3;
            int gh = h0 + row - 2, gw = w0 + col - 2;
            const void* src =
                (u < TOT && (unsigned)gh < (unsigned)H && (unsigned)gw < (unsigned)W)
                ? (const void*)(in + ((size_t)(n * H + gh) * W + gw) * Cin + (ck << 5) + (g8 << 3))
                : (const void*)zg;
            stage16(src, (void*)&xin[c * 64]);
        }
    };

    for (int ck = ck0; ck < ckend; ++ck) {
        if (ck != ck0) __syncthreads();    // all waves done reading old xin
        stage_input(ck);
        __syncthreads();                   // drains DMA -> xin ready

        // this wave's weight base for the chunk; per-tap stride = Co*4 s16x8 units
        const s16x8* wbc = wb + ((size_t)(ck * 25) * Co + co0 + wm * 64 + n16) * 4 + g;

        // 3-slot rotating register ring, 2 taps ahead (static indices via full unroll)
        s16x8 wreg[3][4];
        #pragma unroll
        for (int mt = 0; mt < 4; ++mt) wreg[0][mt] = wbc[mt * 64];
        #pragma unroll
        for (int mt = 0; mt < 4; ++mt) wreg[1][mt] = wbc[(size_t)Co * 4 + mt * 64];

        #pragma unroll
        for (int t = 0; t < 25; ++t) {
            if (t < 23) {
                const s16x8* wn = wbc + (size_t)(t + 2) * Co * 4;
                #pragma unroll
                for (int mt = 0; mt < 4; ++mt) wreg[(t + 2) % 3][mt] = wn[mt * 64];
            }
            const int r = t / 5, s = t - (t / 5) * 5;

            // ---- B-fragments from shared input tile ----
            s16x8 bf[NT];
            #pragma unroll
            for (int nt = 0; nt < NT; ++nt) {
                int row, col;
                if (IS3) { row = ph[nt] + r; col = pw[nt] + s; }
                else {
                    int rr = nt / WC16, cc = nt - rr * WC16;
                    row = rr + r;
                    col = cc * 16 + n16 + s;
                }
                bf[nt] = xin[(row * NC + col) * 4 + ((g + (col >> 1) + row) & 3)];
            }
            __builtin_amdgcn_s_setprio(1);
            #pragma unroll
            for (int mt = 0; mt < 4; ++mt)
                #pragma unroll
                for (int nt = 0; nt < NT; ++nt)
                    acc[mt][nt] = __builtin_amdgcn_mfma_f32_16x16x32_bf16(
                        wreg[t % 3][mt], bf[nt], acc[mt][nt], 0, 0, 0);
            __builtin_amdgcn_s_setprio(0);
        }
    }

    // ---- epilogue: C/D layout col=lane&15 (pos), row=g*4+reg (co) ----
    if (IS3) {
        #pragma unroll
        for (int mt = 0; mt < 4; ++mt) {
            #pragma unroll
            for (int reg = 0; reg < 4; ++reg) {
                const int co = co0 + wm * 64 + mt * 16 + g * 4 + reg;
                #pragma unroll
                for (int nt = 0; nt < NT; ++nt) {
                    int pos = nt * 16 + n16;
                    if (pos < 125)
                        outf[((size_t)(ks * NB + n) * Co + co) * 125 + pos] = acc[mt][nt][reg];
                }
            }
        }
    } else {
        #pragma unroll
        for (int mt = 0; mt < 4; ++mt) {
            const int cobase = co0 + wm * 64 + mt * 16 + g * 4;
            const float b0 = bias[cobase + 0];
            const float b1 = bias[cobase + 1];
            const float b2 = bias[cobase + 2];
            const float b3 = bias[cobase + 3];
            #pragma unroll
            for (int nt = 0; nt < NT; ++nt) {
                int rr = nt / WC16, cc = nt - rr * WC16;
                int h  = h0 + rr;
                int wp = w0 + cc * 16 + n16;
                if (h < H && wp < W) {
                    float v0 = acc[mt][nt][0] + b0;
                    float v1 = acc[mt][nt][1] + b1;
                    float v2 = acc[mt][nt][2] + b2;
                    float v3 = acc[mt][nt][3] + b3;
                    if (leaky) {
                        v0 = (v0 >= 0.f) ? v0 : 0.2f * v0;
                        v1 = (v1 >= 0.f) ? v1 : 0.2f * v1;
                        v2 = (v2 >= 0.f) ? v2 : 0.2f * v2;
                        v3 = (v3 >= 0.f) ? v3 : 0.2f * v3;
                    }
                    ushort4 pkd;
                    pkd.x = (ushort)f2bf(v0);
                    pkd.y = (ushort)f2bf(v1);
                    pkd.z = (ushort)f2bf(v2);
                    pkd.w = (ushort)f2bf(v3);
                    *(ushort4*)(outb + ((size_t)(n * H + h) * W + wp) * Co + cobase) = pkd;
                }
            }
        }
    }
}

// ======================= VLAD partial: softmax assignment + partial einsum =======================
__global__ __launch_bounds__(256) void k_vlad_partial(
    const float* __restrict__ x,        // [N][C][P]
    const float* __restrict__ convw_t,  // [C][K]
    const float* __restrict__ convb,    // [K]
    float* __restrict__ pv,             // [N][125][K][C]
    float* __restrict__ pa)             // [N][125][K]
{
    __shared__ float xs[C_][64];
    __shared__ float als[64][K_];
    __shared__ float pgsum[4][K_];

    const int tid = threadIdx.x;
    const int chunk = blockIdx.x;    // 0..124
    const int n = blockIdx.y;        // 0..15
    const int p0 = chunk * 64;

    const float* xn = x + (size_t)n * C_ * P_ + p0;
    for (int i = tid; i < C_ * 64; i += 256) {
        int c = i >> 6, pp = i & 63;
        xs[c][pp] = xn[(size_t)c * P_ + pp];
    }
    __syncthreads();

    const int k  = tid & 63;
    const int pg = tid >> 6;

    float sa[16];
    const float bk = convb[k];
    #pragma unroll
    for (int j = 0; j < 16; ++j) sa[j] = bk;
    for (int c = 0; c < C_; ++c) {
        float wv = convw_t[c * K_ + k];
        const float4* xp = (const float4*)&xs[c][pg * 16];
        #pragma unroll
        for (int q = 0; q < 4; ++q) {
            float4 xv = xp[q];
            sa[q*4+0] += wv * xv.x;
            sa[q*4+1] += wv * xv.y;
            sa[q*4+2] += wv * xv.z;
            sa[q*4+3] += wv * xv.w;
        }
    }

    float asum_loc = 0.f;
    #pragma unroll
    for (int j = 0; j < 16; ++j) {
        float m = sa[j];
        for (int d = 32; d >= 1; d >>= 1) m = fmaxf(m, __shfl_xor(m, d));
        float e = __expf(sa[j] - m);
        float s = e;
        for (int d = 32; d >= 1; d >>= 1) s += __shfl_xor(s, d);
        float a = e / s;
        als[pg * 16 + j][k] = a;
        asum_loc += a;
    }
    pgsum[pg][k] = asum_loc;
    __syncthreads();
    if (tid < K_) {
        pa[((size_t)n * 125 + chunk) * K_ + tid] =
            pgsum[0][tid] + pgsum[1][tid] + pgsum[2][tid] + pgsum[3][tid];
    }

    const int q = pg;
    float acc[32];
    #pragma unroll
    for (int j = 0; j < 32; ++j) acc[j] = 0.f;
    for (int p = 0; p < 64; p += 4) {
        float a0 = als[p+0][k], a1 = als[p+1][k], a2 = als[p+2][k], a3 = als[p+3][k];
        #pragma unroll
        for (int j = 0; j < 32; ++j) {
            const float4 xv = *(const float4*)&xs[q*32 + j][p];
            acc[j] += a0*xv.x + a1*xv.y + a2*xv.z + a3*xv.w;
        }
    }
    float* pvp = pv + ((((size_t)n * 125 + chunk) * K_ + k) * C_ + q * 32);
    #pragma unroll
    for (int j = 0; j < 32; ++j) pvp[j] = acc[j];
}

__global__ void k_vlad_reduce(const float* __restrict__ pv, float* __restrict__ vlad_raw)
{
    int idx = blockIdx.x * blockDim.x + threadIdx.x;
    if (idx >= NB * 8192) return;
    int n = idx >> 13;
    int rest = idx & 8191;
    const float* p = pv + (size_t)n * 125 * 8192 + rest;
    float s = 0.f;
    for (int ch = 0; ch < 125; ++ch) s += p[(size_t)ch * 8192];
    vlad_raw[(size_t)n * 8192 + rest] = s;
}

__global__ void k_asum_reduce(const float* __restrict__ pa, float* __restrict__ asum)
{
    int idx = blockIdx.x * blockDim.x + threadIdx.x;
    if (idx >= NB * K_) return;
    const float* p = pa + (size_t)(idx >> 6) * 125 * K_ + (idx & 63);
    float s = 0.f;
    for (int ch = 0; ch < 125; ++ch) s += p[ch * K_];
    asum[idx] = s;
}

__global__ __launch_bounds__(128) void k_vlad_finalize(
    const float* __restrict__ vlad_raw, const float* __restrict__ asum,
    const float* __restrict__ centers, float* __restrict__ feat)
{
    __shared__ float red[2];
    const int k = blockIdx.x, n = blockIdx.y, c = threadIdx.x;
    float v = vlad_raw[((size_t)n * K_ + k) * C_ + c] - asum[n * K_ + k] * centers[k * C_ + c];
    float ss = v * v;
    for (int d = 32; d >= 1; d >>= 1) ss += __shfl_xor(ss, d);
    if ((threadIdx.x & 63) == 0) red[threadIdx.x >> 6] = ss;
    __syncthreads();
    float denom = fmaxf(sqrtf(red[0] + red[1]), 1e-12f);
    feat[(size_t)n * 9216 + k * C_ + c] = v / denom;
}

// ======================= max pool, channel-last bf16, 8ch/thread =======================
__global__ void k_maxpool_cl(const ushort* __restrict__ in, ushort* __restrict__ out,
                             int Hi, int Wi, int C8, int ph, int pw, int total)
{
    int idx = blockIdx.x * blockDim.x + threadIdx.x;
    if (idx >= total) return;
    const int Ho = Hi / ph, Wo = Wi / pw;
    const int C = C8 << 3;
    int c8 = idx % C8;
    int t  = idx / C8;
    int wo = t % Wo; t /= Wo;
    int ho = t % Ho;
    int n  = t / Ho;
    const ushort* base = in + ((size_t)(n * Hi + ho * ph) * Wi + wo * pw) * C + (c8 << 3);
    float m[8];
    #pragma unroll
    for (int j = 0; j < 8; ++j) m[j] = -INFINITY;
    for (int r = 0; r < ph; ++r)
        for (int s = 0; s < pw; ++s) {
            s16x8 v = *(const s16x8*)(base + ((size_t)r * Wi + s) * C);
            #pragma unroll
            for (int j = 0; j < 8; ++j) m[j] = fmaxf(m[j], bf2f((ushort)v[j]));
        }
    s16x8 o;
    #pragma unroll
    for (int j = 0; j < 8; ++j) o[j] = f2bf(m[j]);
    *(s16x8*)(out + ((size_t)(n * Ho + ho) * Wo + wo) * C + (c8 << 3)) = o;
}

// conv3 split-K(8) reduce + bias + global 5x25 max pool -> feat[:, 8192:9216]
__global__ void k_pool3_feat(const float* __restrict__ part, const float* __restrict__ bias,
                             float* __restrict__ feat)
{
    int idx = blockIdx.x * blockDim.x + threadIdx.x;   // n*1024 + c
    if (idx >= NB * 1024) return;
    int n = idx >> 10, c = idx & 1023;
    const size_t kstride = (size_t)NB * 1024 * 125;
    const float* p = part + ((size_t)n * 1024 + c) * 125;
    const float b = bias[c];
    float m = -INFINITY;
    for (int i = 0; i < 125; ++i) {
        float s = 0.f;
        #pragma unroll
        for (int ksl = 0; ksl < 8; ++ksl) s += p[i + ksl * kstride];
        m = fmaxf(m, b + s);
    }
    feat[(size_t)n * 9216 + 8192 + c] = m;
}

// ======================= MLP: featnorm -> sliced partial GEMV -> reduce+norm =======================
__global__ __launch_bounds__(256) void k_featnorm(const float* __restrict__ feat,
                                                  float* __restrict__ scale)
{
    __shared__ float r1s[4], r2s[4];
    const int n = blockIdx.x;
    const int tid = threadIdx.x;
    const int wid = tid >> 6;
    float s1 = 0.f, s2 = 0.f;
    const float* f = feat + (size_t)n * 9216;
    for (int i = tid; i < 9216; i += 256) {
        float v = f[i];
        if (i < 8192) s1 += v * v; else s2 += v * v;
    }
    for (int d = 32; d >= 1; d >>= 1) { s1 += __shfl_xor(s1, d); s2 += __shfl_xor(s2, d); }
    if ((tid & 63) == 0) { r1s[wid] = s1; r2s[wid] = s2; }
    __syncthreads();
    if (tid == 0) {
        scale[n * 2 + 0] = 1.f / fmaxf(sqrtf(r1s[0] + r1s[1] + r1s[2] + r1s[3]), 1e-12f);
        scale[n * 2 + 1] = 1.f / fmaxf(sqrtf(r2s[0] + r2s[1] + r2s[2] + r2s[3]), 1e-12f);
    }
}

__global__ __launch_bounds__(256) void k_mlp_part(
    const float* __restrict__ feat, const float* __restrict__ scale,
    const float* __restrict__ wt,   // [9216][256]
    float* __restrict__ part)       // [N][16][256]
{
    __shared__ float fs[576];
    const int n  = blockIdx.x >> 4;
    const int sl = blockIdx.x & 15;
    const int tid = threadIdx.x;
    const int base = sl * 576;
    for (int j = tid; j < 576; j += 256) {
        int idx = base + j;
        fs[j] = feat[(size_t)n * 9216 + idx] * scale[n * 2 + (idx < 8192 ? 0 : 1)];
    }
    __syncthreads();
    float a0 = 0.f, a1 = 0.f;
    for (int j = 0; j < 576; j += 2) {
        a0 += fs[j]     * wt[(size_t)(base + j)     * 256 + tid];
        a1 += fs[j + 1] * wt[(size_t)(base + j + 1) * 256 + tid];
    }
    part[((size_t)n * 16 + sl) * 256 + tid] = a0 + a1;
}

__global__ __launch_bounds__(256) void k_mlp_final(
    const float* __restrict__ part, const float* __restrict__ bias,
    float* __restrict__ outp)
{
    __shared__ float red[4];
    const int n = blockIdx.x;
    const int tid = threadIdx.x;
    float a = bias[tid];
    #pragma unroll
    for (int s = 0; s < 16; ++s) a += part[((size_t)n * 16 + s) * 256 + tid];
    float ss = a * a;
    for (int d = 32; d >= 1; d >>= 1) ss += __shfl_xor(ss, d);
    if ((tid & 63) == 0) red[tid >> 6] = ss;
    __syncthreads();
    const float inv = 1.f / fmaxf(sqrtf(red[0] + red[1] + red[2] + red[3]), 1e-12f);
    outp[n * 256 + tid] = a * inv;
}

// ======================= host launch =======================
extern "C" void kernel_launch(void* const* d_in, const int* in_sizes, int n_in,
                              void* d_out, int out_size, void* d_ws, size_t ws_size,
                              hipStream_t stream)
{
    const float* x      = (const float*)d_in[0];
    const float* cents  = (const float*)d_in[1];
    const float* conv_w = (const float*)d_in[2];
    const float* conv_b = (const float*)d_in[3];
    const float* w1     = (const float*)d_in[4];
    const float* b1     = (const float*)d_in[5];
    const float* w2     = (const float*)d_in[6];
    const float* b2     = (const float*)d_in[7];
    const float* w3     = (const float*)d_in[8];
    const float* b3     = (const float*)d_in[9];
    const float* mlp_w  = (const float*)d_in[10];
    const float* mlp_b  = (const float*)d_in[11];
    float* outp = (float*)d_out;

    char* ws = (char*)d_ws;
    size_t off = 0;
    auto alloc = [&](size_t bytes) -> void* {
        off = (off + 255) & ~(size_t)255;
        void* p = ws + off;
        off += bytes;
        return p;
    };
    ushort* zguard  = (ushort*)alloc(256);
    float*  convw_t = (float*)alloc((size_t)64 * 128 * 4);
    float*  mwt     = (float*)alloc((size_t)9216 * 256 * 4);
    short*  wb1     = (short*)alloc((size_t)819200 * 2);
    short*  wb2     = (short*)alloc((size_t)3276800 * 2);
    short*  wb3     = (short*)alloc((size_t)13107200 * 2);
    ushort* x_cl    = (ushort*)alloc((size_t)NB * 8000 * 128 * 2);      // 32.8 MB
    float*  vlad_raw= (float*)alloc((size_t)NB * 8192 * 4);
    float*  asum    = (float*)alloc((size_t)NB * K_ * 4);
    float*  feat    = (float*)alloc((size_t)NB * 9216 * 4);
    float*  pa      = (float*)alloc((size_t)NB * 125 * K_ * 4);
    float*  scale   = (float*)alloc((size_t)NB * 2 * 4);
    float*  mpart   = (float*)alloc((size_t)NB * 16 * 256 * 4);
    ushort* pool2b  = (ushort*)alloc((size_t)NB * 125 * 512 * 2);       // [n][5][25][512]
    char*   slabA   = (char*)alloc((size_t)8 * NB * 1024 * 125 * 4);    // 65.5 MB multi-use:
                                                                        //  vlad pv f32 / conv outs bf16 / conv3 part3 f32
    ushort* slabB   = (ushort*)alloc((size_t)NB * 2000 * 256 * 2);      // 16.4 MB pool1 out

    hipMemsetAsync(zguard, 0, 256, stream);

    // ---- one-time prep ----
    {
        dim3 blk(32, 8);
        k_transpose_tiled<<<dim3(4, 2), blk, 0, stream>>>(conv_w, convw_t, 64, 128);
        k_transpose_tiled<<<dim3(288, 8), blk, 0, stream>>>(mlp_w, mwt, 256, 9216);
        k_wprep<<<(819200 + 255) / 256, 256, 0, stream>>>(w1, wb1, 256, 128, 819200);
        k_wprep<<<(3276800 + 255) / 256, 256, 0, stream>>>(w2, wb2, 512, 256, 3276800);
        k_wprep<<<(13107200 + 255) / 256, 256, 0, stream>>>(w3, wb3, 1024, 512, 13107200);
        k_nchw_to_nhwc<<<dim3(250, 4, NB), blk, 0, stream>>>(x, x_cl, 128, 8000);
    }

    // ---- VLAD branch (pv in slabA, consumed before conv1 writes it) ----
    k_vlad_partial<<<dim3(125, NB), 256, 0, stream>>>(x, convw_t, conv_b, (float*)slabA, pa);
    k_vlad_reduce<<<(NB * 8192 + 255) / 256, 256, 0, stream>>>((float*)slabA, vlad_raw);
    k_asum_reduce<<<(NB * K_ + 255) / 256, 256, 0, stream>>>(pa, asum);
    k_vlad_finalize<<<dim3(K_, NB), 128, 0, stream>>>(vlad_raw, asum, cents, feat);

    // ---- conv1: 256co x 128pos (4r x 32c); 1120 blocks = 70pos x 1co x 16n; LDS 18.4KB ----
    k_conv_mfma<8, 36, 4, 2, 0><<<1120, 256, 0, stream>>>(
        x_cl, (const s16x8*)wb1, b1, (ushort*)slabA, nullptr, zguard,
        128, 256, 40, 200, 7, 1, 4, /*xpc=*/8, /*PT=*/70);
    {
        int tot = NB * 20 * 100 * 32;   // C8 = 32
        k_maxpool_cl<<<(tot + 255) / 256, 256, 0, stream>>>(
            (ushort*)slabA, slabB, 40, 200, 32, 2, 2, tot);
    }
    // ---- conv2: 256co x 128pos (4r x 32c); 640 blocks = 20pos x 2co x 16n; LDS 18.4KB ----
    k_conv_mfma<8, 36, 4, 2, 0><<<640, 256, 0, stream>>>(
        slabB, (const s16x8*)wb2, b2, (ushort*)slabA, nullptr, zguard,
        256, 512, 20, 100, 4, 1, 8, /*xpc=*/4, /*PT=*/20);
    {
        int tot = NB * 5 * 25 * 64;     // C8 = 64
        k_maxpool_cl<<<(tot + 255) / 256, 256, 0, stream>>>(
            (ushort*)slabA, pool2b, 20, 100, 64, 4, 4, tot);
    }
    // ---- conv3: 256co x whole plane, split-K x8; 512 blocks = 8ks x 4co x 16n; part3 = slabA ----
    k_conv_mfma<9, 29, 4, 2, 1><<<512, 256, 0, stream>>>(
        pool2b, (const s16x8*)wb3, b3, nullptr, (float*)slabA, zguard,
        512, 1024, 5, 25, 1, 0, 2, /*xpc=*/2, /*PT=*/8);
    // ---- split-K(8) reduce + bias + 5x25 max pool -> feat[:, 8192:] ----
    k_pool3_feat<<<(NB * 1024 + 255) / 256, 256, 0, stream>>>((float*)slabA, b3, feat);

    // ---- norms + MLP + final norm ----
    k_featnorm<<<NB, 256, 0, stream>>>(feat, scale);
    k_mlp_part<<<NB * 16, 256, 0, stream>>>(feat, scale, mwt, mpart);
    k_mlp_final<<<NB, 256, 0, stream>>>(mpart, mlp_b, outp);
}